// Round 1
// baseline (283.037 us; speedup 1.0000x reference)
//
#include <hip/hip_runtime.h>
#include <hip/hip_bf16.h>

// GARCH-LSTM fused cell, B=2097152 rows, H=16.
// Layout: 4 threads per row; each thread handles 4 hidden units via float4
// loads/stores of c_prev / c_t (perfectly coalesced, 16 B/lane).
// Memory-bound: 140 B/row ideal -> ~294 MB -> ~47 us floor at 6.3 TB/s.

__device__ __forceinline__ float fsig(float x) {
    // sigmoid via fast exp2-based exp + raw v_rcp_f32 (threshold is 0.112 abs)
    return __builtin_amdgcn_rcpf(1.0f + __expf(-x));
}

__device__ __forceinline__ float ftanh(float x) {
    // tanh(x) = 1 - 2/(exp(2x)+1); saturates correctly at +/-inf of exp
    float t = __expf(2.0f * x);
    return 1.0f - 2.0f * __builtin_amdgcn_rcpf(t + 1.0f);
}

__global__ __launch_bounds__(256) void garch_lstm_kernel(
    const float* __restrict__ eps, const float* __restrict__ sigma2,
    const float* __restrict__ c_prev,
    const float* __restrict__ Wf_w, const float* __restrict__ Wf_b,
    const float* __restrict__ Uf_w, const float* __restrict__ Uf_b,
    const float* __restrict__ Wi_w, const float* __restrict__ Wi_b,
    const float* __restrict__ Ui_w, const float* __restrict__ Ui_b,
    const float* __restrict__ Wc_w, const float* __restrict__ Wc_b,
    const float* __restrict__ Uc_w, const float* __restrict__ Uc_b,
    const float* __restrict__ b_f, const float* __restrict__ b_i,
    const float* __restrict__ b_c, const float* __restrict__ w,
    const float* __restrict__ garch_w, const float* __restrict__ garch_b,
    float* __restrict__ out_s, float* __restrict__ out_c, int nrows)
{
    // Stage combined gate coefficients in LDS once per block:
    // rows 0..2: forget (Wf_w, Uf_w, Wf_b+Uf_b+b_f), 3..5: input, 6..8: cand.
    __shared__ __align__(16) float sW[9][16];
    if (threadIdx.x < 16) {
        const int t = threadIdx.x;
        sW[0][t] = Wf_w[t]; sW[1][t] = Uf_w[t]; sW[2][t] = Wf_b[t] + Uf_b[t] + b_f[0];
        sW[3][t] = Wi_w[t]; sW[4][t] = Ui_w[t]; sW[5][t] = Wi_b[t] + Ui_b[t] + b_i[0];
        sW[6][t] = Wc_w[t]; sW[7][t] = Uc_w[t]; sW[8][t] = Wc_b[t] + Uc_b[t] + b_c[0];
    }
    // Wave-uniform scalars (compiler scalarizes; L1/L3 hits after first wave).
    const float g1 = garch_w[1], g2 = garch_w[2], g3 = garch_w[3];
    const float g0 = garch_w[0] * 1.0f /*SCALE*/ + garch_b[0];
    const float wv = w[0];
    __syncthreads();

    const unsigned tid = blockIdx.x * 256u + threadIdx.x;
    const unsigned row = tid >> 2;
    const unsigned sub = tid & 3u;
    if ((int)row >= nrows) return;

    const float e = eps[row];       // 4 lanes share one address -> one line/wave
    const float s = sigma2[row];

    // Coalesced float4: lane address = base + tid*16
    const float4 cp4 = *(reinterpret_cast<const float4*>(c_prev) + ((size_t)row * 4 + sub));
    float cp[4] = {cp4.x, cp4.y, cp4.z, cp4.w};

    const int h0 = (int)sub * 4;
    float Af[4], Bf[4], Cf[4], Ai[4], Bi[4], Ci[4], Ac[4], Bc[4], Cc[4];
#pragma unroll
    for (int j = 0; j < 4; ++j) {
        Af[j] = sW[0][h0 + j]; Bf[j] = sW[1][h0 + j]; Cf[j] = sW[2][h0 + j];
        Ai[j] = sW[3][h0 + j]; Bi[j] = sW[4][h0 + j]; Ci[j] = sW[5][h0 + j];
        Ac[j] = sW[6][h0 + j]; Bc[j] = sW[7][h0 + j]; Cc[j] = sW[8][h0 + j];
    }

    float cv[4];
    float sum_t = 0.0f;
#pragma unroll
    for (int j = 0; j < 4; ++j) {
        const float pf = fmaf(e, Af[j], fmaf(s, Bf[j], Cf[j]));
        const float pi = fmaf(e, Ai[j], fmaf(s, Bi[j], Ci[j]));
        const float pc = fmaf(e, Ac[j], fmaf(s, Bc[j], Cc[j]));
        const float f_t   = fsig(pf);
        const float i_t   = fsig(pi);
        const float c_hat = fsig(pc);   // reference really uses sigmoid here
        const float c = fmaf(i_t, c_hat, f_t * cp[j]);
        cv[j] = c;
        sum_t += ftanh(c);
    }

    // Coalesced float4 store of c_t
    float4 ct4 = make_float4(cv[0], cv[1], cv[2], cv[3]);
    *(reinterpret_cast<float4*>(out_c) + ((size_t)row * 4 + sub)) = ct4;

    // Reduce tanh-sum across the 4 lanes of this row
    sum_t += __shfl_xor(sum_t, 1, 64);
    sum_t += __shfl_xor(sum_t, 2, 64);

    if (sub == 0) {
        const float e2 = e * e;
        const float asym = (e < 0.0f) ? e2 : 0.0f;
        const float o = fmaf(g1, e2, fmaf(g2, asym, fmaf(g3, s, g0)));
        out_s[row] = o * fmaf(wv, sum_t * 0.0625f, 1.0f);
    }
}

extern "C" void kernel_launch(void* const* d_in, const int* in_sizes, int n_in,
                              void* d_out, int out_size, void* d_ws, size_t ws_size,
                              hipStream_t stream) {
    // setup_inputs() dict order:
    // 0 eps, 1 sigma2, 2 c_prev, 3..14 {Wf_w,Wf_b,Uf_w,Uf_b,Wi_w,Wi_b,Ui_w,Ui_b,
    // Wc_w,Wc_b,Uc_w,Uc_b}, 15 b_f, 16 b_i, 17 b_c, 18 w, 19 garch_w, 20 garch_b
    const float* eps     = (const float*)d_in[0];
    const float* sigma2  = (const float*)d_in[1];
    const float* c_prev  = (const float*)d_in[2];
    const float* Wf_w    = (const float*)d_in[3];
    const float* Wf_b    = (const float*)d_in[4];
    const float* Uf_w    = (const float*)d_in[5];
    const float* Uf_b    = (const float*)d_in[6];
    const float* Wi_w    = (const float*)d_in[7];
    const float* Wi_b    = (const float*)d_in[8];
    const float* Ui_w    = (const float*)d_in[9];
    const float* Ui_b    = (const float*)d_in[10];
    const float* Wc_w    = (const float*)d_in[11];
    const float* Wc_b    = (const float*)d_in[12];
    const float* Uc_w    = (const float*)d_in[13];
    const float* Uc_b    = (const float*)d_in[14];
    const float* b_f     = (const float*)d_in[15];
    const float* b_i     = (const float*)d_in[16];
    const float* b_c     = (const float*)d_in[17];
    const float* wp      = (const float*)d_in[18];
    const float* garch_w = (const float*)d_in[19];
    const float* garch_b = (const float*)d_in[20];

    const int n = in_sizes[0];          // B = 2097152
    float* out_s = (float*)d_out;       // (B,1) first in return order
    float* out_c = out_s + n;           // (B,16) second

    const int threads = 256;
    const long long total = (long long)n * 4;   // 4 threads per row
    const int blocks = (int)((total + threads - 1) / threads);

    garch_lstm_kernel<<<blocks, threads, 0, stream>>>(
        eps, sigma2, c_prev,
        Wf_w, Wf_b, Uf_w, Uf_b, Wi_w, Wi_b, Ui_w, Ui_b,
        Wc_w, Wc_b, Uc_w, Uc_b, b_f, b_i, b_c, wp, garch_w, garch_b,
        out_s, out_c, n);
}

// Round 2
// 282.515 us; speedup vs baseline: 1.0018x; 1.0018x over previous
//
#include <hip/hip_runtime.h>
#include <hip/hip_bf16.h>

// GARCH-LSTM fused cell, B=2097152 rows, H=16.
// Layout: 4 threads per row; each thread handles 4 hidden units via float4
// loads/stores of c_prev / c_t (perfectly coalesced, 16 B/lane).
// Memory-bound: 140 B/row ideal -> ~294 MB -> ~47 us floor at 6.3 TB/s.
// R2 change: coefficient reads from LDS as float4 (ds_read_b128, 9/thread)
// instead of 36 scalar ds_read_b32 -> LDS issue time ~44us -> ~11us, below
// the HBM floor.

__device__ __forceinline__ float fsig(float x) {
    // sigmoid via fast exp2-based exp + raw v_rcp_f32 (abs threshold is 0.112)
    return __builtin_amdgcn_rcpf(1.0f + __expf(-x));
}

__device__ __forceinline__ float ftanh(float x) {
    // tanh(x) = 1 - 2/(exp(2x)+1); saturates correctly via exp overflow
    float t = __expf(2.0f * x);
    return 1.0f - 2.0f * __builtin_amdgcn_rcpf(t + 1.0f);
}

__global__ __launch_bounds__(256) void garch_lstm_kernel(
    const float* __restrict__ eps, const float* __restrict__ sigma2,
    const float* __restrict__ c_prev,
    const float* __restrict__ Wf_w, const float* __restrict__ Wf_b,
    const float* __restrict__ Uf_w, const float* __restrict__ Uf_b,
    const float* __restrict__ Wi_w, const float* __restrict__ Wi_b,
    const float* __restrict__ Ui_w, const float* __restrict__ Ui_b,
    const float* __restrict__ Wc_w, const float* __restrict__ Wc_b,
    const float* __restrict__ Uc_w, const float* __restrict__ Uc_b,
    const float* __restrict__ b_f, const float* __restrict__ b_i,
    const float* __restrict__ b_c, const float* __restrict__ w,
    const float* __restrict__ garch_w, const float* __restrict__ garch_b,
    float* __restrict__ out_s, float* __restrict__ out_c, int nrows)
{
    // Stage combined gate coefficients in LDS once per block:
    // rows 0..2: forget (Wf_w, Uf_w, Wf_b+Uf_b+b_f), 3..5: input, 6..8: cand.
    __shared__ __align__(16) float sW[9][16];
    if (threadIdx.x < 16) {
        const int t = threadIdx.x;
        sW[0][t] = Wf_w[t]; sW[1][t] = Uf_w[t]; sW[2][t] = Wf_b[t] + Uf_b[t] + b_f[0];
        sW[3][t] = Wi_w[t]; sW[4][t] = Ui_w[t]; sW[5][t] = Wi_b[t] + Ui_b[t] + b_i[0];
        sW[6][t] = Wc_w[t]; sW[7][t] = Uc_w[t]; sW[8][t] = Wc_b[t] + Uc_b[t] + b_c[0];
    }
    // Wave-uniform scalars (compiler scalarizes; L2-resident after first wave).
    const float g1 = garch_w[1], g2 = garch_w[2], g3 = garch_w[3];
    const float g0 = garch_w[0] /*×SCALE=1*/ + garch_b[0];
    const float wv = w[0];
    __syncthreads();

    const unsigned tid = blockIdx.x * 256u + threadIdx.x;
    const unsigned row = tid >> 2;
    const unsigned sub = tid & 3u;
    if ((int)row >= nrows) return;

    const float e = eps[row];       // 4 lanes share one address -> 64B/wave
    const float s = sigma2[row];

    // Coalesced float4: lane address = base + tid*16  (row*4+sub == tid)
    const float4 cp4 = *(reinterpret_cast<const float4*>(c_prev) + ((size_t)row * 4 + sub));
    float cp[4] = {cp4.x, cp4.y, cp4.z, cp4.w};

    // 9 ds_read_b128: each thread's 4 columns are contiguous & 16B-aligned.
    const int h0 = (int)sub * 4;
    float Af[4], Bf[4], Cf[4], Ai[4], Bi[4], Ci[4], Ac[4], Bc[4], Cc[4];
    *reinterpret_cast<float4*>(Af) = *reinterpret_cast<const float4*>(&sW[0][h0]);
    *reinterpret_cast<float4*>(Bf) = *reinterpret_cast<const float4*>(&sW[1][h0]);
    *reinterpret_cast<float4*>(Cf) = *reinterpret_cast<const float4*>(&sW[2][h0]);
    *reinterpret_cast<float4*>(Ai) = *reinterpret_cast<const float4*>(&sW[3][h0]);
    *reinterpret_cast<float4*>(Bi) = *reinterpret_cast<const float4*>(&sW[4][h0]);
    *reinterpret_cast<float4*>(Ci) = *reinterpret_cast<const float4*>(&sW[5][h0]);
    *reinterpret_cast<float4*>(Ac) = *reinterpret_cast<const float4*>(&sW[6][h0]);
    *reinterpret_cast<float4*>(Bc) = *reinterpret_cast<const float4*>(&sW[7][h0]);
    *reinterpret_cast<float4*>(Cc) = *reinterpret_cast<const float4*>(&sW[8][h0]);

    float cv[4];
    float sum_t = 0.0f;
#pragma unroll
    for (int j = 0; j < 4; ++j) {
        const float pf = fmaf(e, Af[j], fmaf(s, Bf[j], Cf[j]));
        const float pi = fmaf(e, Ai[j], fmaf(s, Bi[j], Ci[j]));
        const float pc = fmaf(e, Ac[j], fmaf(s, Bc[j], Cc[j]));
        const float f_t   = fsig(pf);
        const float i_t   = fsig(pi);
        const float c_hat = fsig(pc);   // reference uses sigmoid for c_hat
        const float c = fmaf(i_t, c_hat, f_t * cp[j]);
        cv[j] = c;
        sum_t += ftanh(c);
    }

    // Coalesced float4 store of c_t
    float4 ct4 = make_float4(cv[0], cv[1], cv[2], cv[3]);
    *(reinterpret_cast<float4*>(out_c) + ((size_t)row * 4 + sub)) = ct4;

    // Reduce tanh-sum across the 4 lanes of this row
    sum_t += __shfl_xor(sum_t, 1, 64);
    sum_t += __shfl_xor(sum_t, 2, 64);

    if (sub == 0) {
        const float e2 = e * e;
        const float asym = (e < 0.0f) ? e2 : 0.0f;
        const float o = fmaf(g1, e2, fmaf(g2, asym, fmaf(g3, s, g0)));
        // 16 active lanes/wave, addresses span one 64B line -> coalesced.
        out_s[row] = o * fmaf(wv, sum_t * 0.0625f, 1.0f);
    }
}

extern "C" void kernel_launch(void* const* d_in, const int* in_sizes, int n_in,
                              void* d_out, int out_size, void* d_ws, size_t ws_size,
                              hipStream_t stream) {
    // setup_inputs() dict order:
    // 0 eps, 1 sigma2, 2 c_prev, 3..14 {Wf_w,Wf_b,Uf_w,Uf_b,Wi_w,Wi_b,Ui_w,Ui_b,
    // Wc_w,Wc_b,Uc_w,Uc_b}, 15 b_f, 16 b_i, 17 b_c, 18 w, 19 garch_w, 20 garch_b
    const float* eps     = (const float*)d_in[0];
    const float* sigma2  = (const float*)d_in[1];
    const float* c_prev  = (const float*)d_in[2];
    const float* Wf_w    = (const float*)d_in[3];
    const float* Wf_b    = (const float*)d_in[4];
    const float* Uf_w    = (const float*)d_in[5];
    const float* Uf_b    = (const float*)d_in[6];
    const float* Wi_w    = (const float*)d_in[7];
    const float* Wi_b    = (const float*)d_in[8];
    const float* Ui_w    = (const float*)d_in[9];
    const float* Ui_b    = (const float*)d_in[10];
    const float* Wc_w    = (const float*)d_in[11];
    const float* Wc_b    = (const float*)d_in[12];
    const float* Uc_w    = (const float*)d_in[13];
    const float* Uc_b    = (const float*)d_in[14];
    const float* b_f     = (const float*)d_in[15];
    const float* b_i     = (const float*)d_in[16];
    const float* b_c     = (const float*)d_in[17];
    const float* wp      = (const float*)d_in[18];
    const float* garch_w = (const float*)d_in[19];
    const float* garch_b = (const float*)d_in[20];

    const int n = in_sizes[0];          // B = 2097152
    float* out_s = (float*)d_out;       // (B,1) first in return order
    float* out_c = out_s + n;           // (B,16) second

    const int threads = 256;
    const long long total = (long long)n * 4;   // 4 threads per row
    const int blocks = (int)((total + threads - 1) / threads);

    garch_lstm_kernel<<<blocks, threads, 0, stream>>>(
        eps, sigma2, c_prev,
        Wf_w, Wf_b, Uf_w, Uf_b, Wi_w, Wi_b, Ui_w, Ui_b,
        Wc_w, Wc_b, Uc_w, Uc_b, b_f, b_i, b_c, wp, garch_w, garch_b,
        out_s, out_c, n);
}